// Round 18
// baseline (136.535 us; speedup 1.0000x reference)
//
#include <hip/hip_runtime.h>
#include <cstdint>
#include <cstddef>

typedef __attribute__((ext_vector_type(8))) short short8;
typedef __attribute__((ext_vector_type(4))) float f32x4;

constexpr int Bn = 64, Tn = 1024, Hn = 256, Kn = 4;
constexpr int TT = 64;             // T-rows per block
constexpr int AROWS = TT + 2;      // 66 staged x-rows (t0-1 .. t0+64)
constexpr int ARSTR = 144;         // A-LDS row stride bytes (hi 64 + lo 64 + 16 pad)
constexpr int ABUFSZ = AROWS * ARSTR;   // 9,504 B per buffer

// round-to-nearest-even fp32 -> bf16 bits
__device__ __forceinline__ unsigned bf16rne(float f) {
  unsigned u = __float_as_uint(f);
  return (u + 0x7fffu + ((u >> 16) & 1u)) >> 16;
}

// Pack conv_w into MFMA-B-fragment-ready hi/lo bf16 (verified since r11):
// Bp[fid(24 ks x 2 p x 16 nf)][lane(64)][j(8)], value = part_p(conv_w[n][i][dt])
// where k = ks*32 + (lane>>4)*8 + j (dt=k>>8, i=k&255), n = nf*16 + (lane&15).
__global__ __launch_bounds__(256) void pack_b_k(const float* __restrict__ conv_w,
                                                unsigned short* __restrict__ Bp) {
  int gt = blockIdx.x * 256 + threadIdx.x;
  int fid = gt >> 6, l = gt & 63;
  int ks = fid >> 5, rem = fid & 31;
  int p = rem >> 4, nf = rem & 15;
  int n = nf * 16 + (l & 15);
  int k0 = ks * 32 + ((l >> 4) << 3);
  short8 s;
  #pragma unroll
  for (int j = 0; j < 8; ++j) {
    int k = k0 + j;
    int dt = k >> 8, i = k & 255;
    float w = conv_w[n * 768 + i * 3 + dt];
    unsigned hb = bf16rne(w);
    if (p == 0) s[j] = (short)hb;
    else        s[j] = (short)bf16rne(w - __uint_as_float(hb << 16));
  }
  *reinterpret_cast<short8*>(Bp + (size_t)fid * 512 + l * 8) = s;
}

// lgkm-only barrier: ds_writes visible, global VGPR loads keep flying.
#define GBAR() asm volatile("s_waitcnt lgkmcnt(0)\n\ts_barrier" ::: "memory")

// Fused conv1d(k=3,pad=1)+bias+ReLU+Linear(256->4) via bf16 3-way-split MFMA
// (AhBh + AlBh + AhBl; dropped AlBl <= 2^-18 relative).
// Block: 64(T) x 128(N), 4 waves (32x64 each = 2x4 16x16 frags, acc=32).
// A: hi/lo bf16, double-buffered LDS (2 x 9,504 B), 8 groups of 32 chans.
// B: THREE-set rotation (A,B,C) -> prefetch distance = 2 STEPs (~200+ cyc),
//    covering L2 latency that the 1-STEP distance of rounds 13-17 exposed.
//    ks schedule: ks(s) = (s%3)*8 + s/3; set index s%3 is static per unroll.
// Per-acc FP order: +AhBh, +AlBh, +AhBl (bitwise = rounds 11-17).
__global__ __launch_bounds__(256, 2) void emis_k(const float* __restrict__ x,
    const unsigned short* __restrict__ Bp, const float* __restrict__ conv_b,
    const float* __restrict__ lin_w, float* __restrict__ em2) {
  __shared__ __align__(16) char A_lds[2 * ABUFSZ];   // 19,008 B

  const int b = blockIdx.z, ny = blockIdx.y, t0 = blockIdx.x * TT;
  const int tid = threadIdx.x, lane = tid & 63, w = tid >> 6;
  const int wm = w >> 1, wn = w & 1;
  const float* xb = x + (size_t)b * Tn * Hn;

  float4 pre[3];                    // A-prefetch regs (12 VGPR)

  // issue group ig's global loads (66 rows x 8 float4 = 528 chunks)
  auto loadA = [&](int ig) {
    #pragma unroll
    for (int it = 0; it < 3; ++it) {
      int idx = it * 256 + tid;
      if (idx < AROWS * 8) {
        int row = idx >> 3, c4 = idx & 7;
        int trow = t0 - 1 + row;
        float4 v = make_float4(0.f, 0.f, 0.f, 0.f);
        if (trow >= 0 && trow < Tn)
          v = *reinterpret_cast<const float4*>(xb + (size_t)trow * Hn + ig * 32 + c4 * 4);
        pre[it] = v;
      }
    }
  };
  // convert + write pre[] into buffer at byte offset boff
  auto writeA = [&](int boff) {
    #pragma unroll
    for (int it = 0; it < 3; ++it) {
      int idx = it * 256 + tid;
      if (idx < AROWS * 8) {
        int row = idx >> 3, c4 = idx & 7;
        float vf[4] = {pre[it].x, pre[it].y, pre[it].z, pre[it].w};
        unsigned h[4], lo[4];
        #pragma unroll
        for (int q = 0; q < 4; ++q) {
          h[q] = bf16rne(vf[q]);
          lo[q] = bf16rne(vf[q] - __uint_as_float(h[q] << 16));
        }
        uint2 hp, lp;
        hp.x = h[0] | (h[1] << 16);  hp.y = h[2] | (h[3] << 16);
        lp.x = lo[0] | (lo[1] << 16); lp.y = lo[2] | (lo[3] << 16);
        char* base = A_lds + boff + row * ARSTR + c4 * 8;
        *reinterpret_cast<uint2*>(base) = hp;        // hi plane
        *reinterpret_cast<uint2*>(base + 64) = lp;   // lo plane
      }
    }
  };

  // B-fragment source base for this wave (4 nf x 2 p frags per step)
  const char* bsrc = reinterpret_cast<const char*>(Bp)
      + (size_t)(ny * 8 + wn * 4) * 1024 + lane * 16;
  auto loadB = [&](short8* Bh, short8* Bl, int ks) {
    #pragma unroll
    for (int nf = 0; nf < 4; ++nf) {
      Bh[nf] = *reinterpret_cast<const short8*>(bsrc + (size_t)((ks * 2 + 0) * 16 + nf) * 1024);
      Bl[nf] = *reinterpret_cast<const short8*>(bsrc + (size_t)((ks * 2 + 1) * 16 + nf) * 1024);
    }
  };

  f32x4 acc[2][4];
  #pragma unroll
  for (int mf = 0; mf < 2; ++mf)
    #pragma unroll
    for (int nf = 0; nf < 4; ++nf) acc[mf][nf] = (f32x4)0.f;

  // per-lane A base: row=(lane&15)+wm*32, k-chans=(lane>>4)*8 (16B)
  const char* aB = A_lds + (lane & 15) * ARSTR + ((lane >> 4) << 4) + wm * 32 * ARSTR;

  short8 BhA[4], BlA[4], BhB[4], BlB[4], BhC[4], BlC[4];

// one K-step in buffer ABUF: consume (BH,BL) prefetched TWO steps ago;
// prefetch ks KSN into (NBH,NBL) for consumption two steps ahead.
#define STEP(ABUF, DT, BH, BL, NBH, NBL, KSN)                                 \
  {                                                                           \
    loadB(NBH, NBL, (KSN));                                                   \
    __builtin_amdgcn_s_setprio(1);                                            \
    _Pragma("unroll")                                                         \
    for (int mf = 0; mf < 2; ++mf) {                                          \
      const char* ap = aB + (ABUF) + (mf * 16 + (DT)) * ARSTR;                \
      short8 Ah = *reinterpret_cast<const short8*>(ap);                       \
      short8 Al = *reinterpret_cast<const short8*>(ap + 64);                  \
      _Pragma("unroll")                                                       \
      for (int nf = 0; nf < 4; ++nf) {                                        \
        f32x4 c = acc[mf][nf];                                                \
        c = __builtin_amdgcn_mfma_f32_16x16x32_bf16(Ah, BH[nf], c, 0, 0, 0);  \
        c = __builtin_amdgcn_mfma_f32_16x16x32_bf16(Al, BH[nf], c, 0, 0, 0);  \
        c = __builtin_amdgcn_mfma_f32_16x16x32_bf16(Ah, BL[nf], c, 0, 0, 0);  \
        acc[mf][nf] = c;                                                      \
      }                                                                       \
    }                                                                         \
    __builtin_amdgcn_s_setprio(0);                                            \
  }

  // prologue: A group 0 -> buf0; B sets A (ks=0) and B (ks=8) in flight
  loadA(0);
  loadB(BhA, BlA, 0);
  loadB(BhB, BlB, 8);
  writeA(0);
  GBAR();

  #pragma unroll 1
  for (int igp = 0; igp < 4; ++igp) {
    const int ig0 = igp * 2, ig1 = ig0 + 1;
    // ---- group ig0 in buf0: consume A,B,C (ks = ig0, 8+ig0, 16+ig0) ----
    loadA(ig1);                                  // issue-early for buf1
    STEP(0, 0, BhA, BlA, BhC, BlC, 16 + ig0);
    STEP(0, 1, BhB, BlB, BhA, BlA, ig1);
    STEP(0, 2, BhC, BlC, BhB, BlB, 8 + ig1);
    writeA(ABUFSZ);                              // write-late into buf1
    GBAR();
    // ---- group ig1 in buf1: consume A,B,C (ks = ig1, 8+ig1, 16+ig1) ----
    if (ig1 < 7) loadA(ig1 + 1);
    STEP(ABUFSZ, 0, BhA, BlA, BhC, BlC, 16 + ig1);
    STEP(ABUFSZ, 1, BhB, BlB, BhA, BlA, (ig1 < 7 ? ig0 + 2 : 0));
    STEP(ABUFSZ, 2, BhC, BlC, BhB, BlB, (ig1 < 7 ? 8 + ig0 + 2 : 0));
    if (ig1 < 7) writeA(0);
    GBAR();
  }
#undef STEP

  // ---- Epilogue: +conv_b, ReLU, x lin_w^T partials over this wave's cols ----
  // C/D layout: col = lane&15, row = (lane>>4)*4 + v  (m89-verified).
  f32x4 pem[2][4];   // [mf][v] -> 4 kk partial sums
  #pragma unroll
  for (int mf = 0; mf < 2; ++mf)
    #pragma unroll
    for (int v = 0; v < 4; ++v) pem[mf][v] = (f32x4)0.f;

  #pragma unroll
  for (int nf = 0; nf < 4; ++nf) {
    const int gcol = ny * 128 + wn * 64 + nf * 16 + (lane & 15);
    const float cb = conv_b[gcol];
    f32x4 lw;
    lw[0] = lin_w[gcol]; lw[1] = lin_w[256 + gcol];
    lw[2] = lin_w[512 + gcol]; lw[3] = lin_w[768 + gcol];
    #pragma unroll
    for (int mf = 0; mf < 2; ++mf)
      #pragma unroll
      for (int v = 0; v < 4; ++v) {
        float val = fmaxf(acc[mf][nf][v] + cb, 0.f);
        pem[mf][v] += val * lw;
      }
  }
  // reduce over the 16 col-lanes (lane bits 0..3)
  #pragma unroll
  for (int mf = 0; mf < 2; ++mf)
    #pragma unroll
    for (int v = 0; v < 4; ++v) {
      f32x4 t = pem[mf][v];
      #pragma unroll
      for (int m = 1; m < 16; m <<= 1) {
        f32x4 q;
        q[0] = __shfl_xor(t[0], m); q[1] = __shfl_xor(t[1], m);
        q[2] = __shfl_xor(t[2], m); q[3] = __shfl_xor(t[3], m);
        t += q;
      }
      pem[mf][v] = t;
    }
  __syncthreads();                    // all waves done with A_lds (reuse)
  // cross-wave (wn) combine via LDS: red[64 rows][2 wn][4 kk]
  float* red = reinterpret_cast<float*>(A_lds);
  if ((lane & 15) == 0) {
    const int g = lane >> 4;
    #pragma unroll
    for (int mf = 0; mf < 2; ++mf)
      #pragma unroll
      for (int v = 0; v < 4; ++v) {
        int r = wm * 32 + mf * 16 + g * 4 + v;
        *reinterpret_cast<f32x4*>(red + (r * 2 + wn) * 4) = pem[mf][v];
      }
  }
  __syncthreads();
  if (tid < TT) {
    f32x4 s0 = *reinterpret_cast<f32x4*>(red + tid * 8);
    f32x4 s1 = *reinterpret_cast<f32x4*>(red + tid * 8 + 4);
    f32x4 s = s0 + s1;
    *reinterpret_cast<f32x4*>(em2 + ((size_t)(b * Tn + t0 + tid) * 2 + ny) * 4) = s;
  }
}

// byte-map composition c(k) = a(b(k))
__device__ __forceinline__ unsigned int compose_map(unsigned int a, unsigned int b) {
#if __has_builtin(__builtin_amdgcn_perm)
  return __builtin_amdgcn_perm(a, a, b);
#else
  unsigned int c = 0;
  #pragma unroll
  for (int k = 0; k < 4; ++k) {
    unsigned int sel = (b >> (8 * k)) & 0xffu;
    c |= ((a >> (8 * sel)) & 0xffu) << (8 * k);
  }
  return c;
#endif
}

// quad_perm broadcast of lane J (within each 4-lane quad) via DPP
template <int J>
__device__ __forceinline__ float qb(float v) {
  return __int_as_float(__builtin_amdgcn_update_dpp(
      0, __float_as_int(v), (J * 0x55), 0xf, 0xf, true));
}

// One quad-parallel Viterbi step for lane k (values bitwise = scalar form).
#define PSTEP(EV, T)                                                       \
  {                                                                        \
    shf[((T) - 1) * 4 + kk] = s;                                           \
    float c0 = qb<0>(s) + trc0;                                            \
    float c1 = qb<1>(s) + trc1;                                            \
    float c2 = qb<2>(s) + trc2;                                            \
    float c3 = qb<3>(s) + trc3;                                            \
    s = fmaxf(fmaxf(c0, c1), fmaxf(c2, c3)) + (EV);                        \
  }

// CRF Viterbi decode. Stage: se[t] = em2[t][half0] + em2[t][half1] + lin_b.
// Forward: 4-lane quad-parallel scan. Backtrace: 64 lanes rebuild argmax
// maps, v_perm suffix-scan (integer-exact).
__global__ __launch_bounds__(64) void viterbi_k(const float* __restrict__ em2,
    const float* __restrict__ lin_b, const float* __restrict__ cstart,
    const float* __restrict__ cend, const float* __restrict__ ctrans,
    int* __restrict__ out) {
  __shared__ float4 se[Tn];          // emissions, 16 KB
  __shared__ float4 sh[Tn - 1];      // score vector BEFORE step t+1, 16 KB
  __shared__ int s_last;
  const int b = blockIdx.x, lane = threadIdx.x;
  const float4* e2 = reinterpret_cast<const float4*>(em2 + (size_t)b * Tn * 8);
  const float lb0 = lin_b[0], lb1 = lin_b[1], lb2 = lin_b[2], lb3 = lin_b[3];
  for (int i = lane; i < Tn; i += 64) {
    float4 a = e2[i * 2], c = e2[i * 2 + 1];
    se[i] = make_float4(a.x + c.x + lb0, a.y + c.y + lb1,
                        a.z + c.z + lb2, a.w + c.w + lb3);
  }
  float tr[4][4];
  #pragma unroll
  for (int j = 0; j < 4; ++j)
    #pragma unroll
    for (int k = 0; k < 4; ++k) tr[j][k] = ctrans[j * 4 + k];
  __syncthreads();

  if (lane < 4) {
    const int kk = lane;
    const float* sef = reinterpret_cast<const float*>(se);
    float* shf = reinterpret_cast<float*>(sh);
    const float trc0 = ctrans[0 * 4 + kk];
    const float trc1 = ctrans[1 * 4 + kk];
    const float trc2 = ctrans[2 * 4 + kk];
    const float trc3 = ctrans[3 * 4 + kk];
    float s = cstart[kk] + sef[kk];
    float e[8];
    #pragma unroll
    for (int d = 0; d < 8; ++d) e[d] = sef[(1 + d) * 4 + kk];
    int t = 1;
    #pragma unroll 1
    for (int g = 0; g < 127; ++g, t += 8) {   // t = 1..1016
      float f[8];
      #pragma unroll
      for (int d = 0; d < 8; ++d) f[d] = e[d];
      #pragma unroll
      for (int d = 0; d < 8; ++d) e[d] = sef[(t + 8 + d) * 4 + kk];
      PSTEP(f[0], t);     PSTEP(f[1], t + 1);
      PSTEP(f[2], t + 2); PSTEP(f[3], t + 3);
      PSTEP(f[4], t + 4); PSTEP(f[5], t + 5);
      PSTEP(f[6], t + 6); PSTEP(f[7], t + 7);
    }
    PSTEP(e[0], 1017); PSTEP(e[1], 1018); PSTEP(e[2], 1019);
    PSTEP(e[3], 1020); PSTEP(e[4], 1021); PSTEP(e[5], 1022);
    PSTEP(e[6], 1023);
    s += cend[kk];
    float f0 = __shfl(s, 0), f1 = __shfl(s, 1);
    float f2 = __shfl(s, 2), f3 = __shfl(s, 3);
    if (kk == 0) {
      int tag = 0; float bf = f0;
      if (f1 > bf) { bf = f1; tag = 1; }
      if (f2 > bf) { bf = f2; tag = 2; }
      if (f3 > bf) { bf = f3; tag = 3; }
      s_last = tag;
    }
  }
  __syncthreads();

  const unsigned int ID = 0x03020100u;
  unsigned int mloc[16];
  const int t0 = lane * 16;
  #pragma unroll
  for (int k = 0; k < 16; ++k) {
    const int t = t0 + k;
    if (t < Tn - 1) {
      const float4 s = sh[t];
      const float4 e = se[t + 1];
      const float sj[4] = {s.x, s.y, s.z, s.w};
      const float ev[4] = {e.x, e.y, e.z, e.w};
      unsigned int mw = 0;
      #pragma unroll
      for (int kk = 0; kk < 4; ++kk) {
        float best = (sj[0] + tr[0][kk]) + ev[kk];
        int bi = 0;
        #pragma unroll
        for (int j = 1; j < 4; ++j) {
          float cc = (sj[j] + tr[j][kk]) + ev[kk];
          if (cc > best) { best = cc; bi = j; }
        }
        mw |= (unsigned)bi << (8 * kk);
      }
      mloc[k] = mw;
    } else {
      mloc[k] = ID;
    }
  }
  unsigned int P = mloc[15];
  #pragma unroll
  for (int k = 14; k >= 0; --k) P = compose_map(mloc[k], P);
  #pragma unroll
  for (int d = 1; d < 64; d <<= 1) {
    unsigned int q = (unsigned int)__shfl_down((int)P, d);
    if (lane + d > 63) q = ID;
    P = compose_map(P, q);
  }
  unsigned int E = (unsigned int)__shfl_down((int)P, 1);
  if (lane == 63) E = ID;
  const int last = s_last;
  unsigned int tag = (E >> (8 * last)) & 3u;
  int* ob = out + (size_t)b * Tn;
  #pragma unroll
  for (int k = 15; k >= 0; --k) {
    tag = (mloc[k] >> (8 * tag)) & 3u;
    ob[t0 + k] = (int)tag;
  }
}

extern "C" void kernel_launch(void* const* d_in, const int* in_sizes, int n_in,
                              void* d_out, int out_size, void* d_ws, size_t ws_size,
                              hipStream_t stream) {
  const float* x      = (const float*)d_in[0];
  const float* conv_w = (const float*)d_in[1];
  const float* conv_b = (const float*)d_in[2];
  const float* lin_w  = (const float*)d_in[3];
  const float* lin_b  = (const float*)d_in[4];
  const float* cstart = (const float*)d_in[5];
  const float* cend   = (const float*)d_in[6];
  const float* ctrans = (const float*)d_in[7];
  int* out = (int*)d_out;

  unsigned short* Bp = (unsigned short*)d_ws;              // 786,432 B
  float* em2 = (float*)((char*)d_ws + 786432);             // 2 MB partials

  pack_b_k<<<192, 256, 0, stream>>>(conv_w, Bp);
  emis_k<<<dim3(Tn / TT, 2, Bn), 256, 0, stream>>>(x, Bp, conv_b, lin_w, em2);
  viterbi_k<<<Bn, 64, 0, stream>>>(em2, lin_b, cstart, cend, ctrans, out);
}